// Round 9
// baseline (1156.240 us; speedup 1.0000x reference)
//
#include <hip/hip_runtime.h>
#include <hip/hip_bf16.h>
#include <cstdint>
#include <cstddef>

// MoE: N=8192 tokens, D=1024, H=2048, O=1024, E=8 experts, G=256 gate hidden, K=2
#define N_TOK 8192
#define D_IN  1024
#define H_DIM 2048
#define O_DIM 1024
#define E_NUM 8
#define G_DIM 256
#define MAXTILES 136            // ceil(16384/128) + 8 experts padding worst case
#define MAXROWS  (MAXTILES*128) // 17408

typedef __attribute__((ext_vector_type(8))) __bf16 bf16x8;
typedef __attribute__((ext_vector_type(4))) float floatx4;

#define GCAST(p) ((__attribute__((address_space(1))) void*)(void*)(p))
#define LCAST(p) ((__attribute__((address_space(3))) void*)(p))

// ---- fused prep kernel: gate1 (512) | cast_x (4096) | trW1 (4096)
#define JOB_G1_END   512
#define JOB_CAST_END 4608
#define JOB_W1_END   8704

// 64x64 fp32 transpose tile, rotation-swizzled: element (r, c) stored at
// tl[r][(c + 8*(r>>3)) & 63].  Reads (8 rows kg*8+j, col c) hit 2 lanes/bank;
// output writes are 128 B contiguous per row (8 lanes x 16 B).
__device__ inline void transpose_body(const float* __restrict__ src,
                                      __bf16* __restrict__ dst,
                                      int K, int N, int e, int ktile, int ntile,
                                      float* smemf) {
  float (*tl)[64] = (float(*)[64])smemf;  // 16384 B
  const float* s = src + (size_t)e * K * N;
  __bf16* d = dst + (size_t)e * K * N;
  int k0 = ktile * 64, n0 = ntile * 64;
  int t = threadIdx.x;
  int kr = t >> 4, nc = t & 15;
#pragma unroll
  for (int p = 0; p < 4; p++) {
    int r = kr + p * 16;
    float4 v = *reinterpret_cast<const float4*>(
        s + (size_t)(k0 + r) * N + n0 + nc * 4);
    *reinterpret_cast<float4*>(&tl[r][(nc * 4 + 8 * (r >> 3)) & 63]) = v;
  }
  __syncthreads();
  int n = t >> 3, kg = t & 7;
#pragma unroll
  for (int p = 0; p < 2; p++) {
    int c = n + p * 32;
    bf16x8 o;
#pragma unroll
    for (int j = 0; j < 8; j++)
      o[j] = (__bf16)tl[kg * 8 + j][(c + 8 * kg) & 63];
    *reinterpret_cast<bf16x8*>(d + (size_t)(n0 + c) * K + k0 + kg * 8) = o;
  }
}

__device__ inline void gate1_body(const float* __restrict__ x,
                                  const float* __restrict__ Wg1,
                                  const float* __restrict__ bg1,
                                  float* __restrict__ g,
                                  int bn, int bm, float* smemf) {
  float (*As)[68] = (float(*)[68])smemf;            // 32 x 68
  float (*Bs)[68] = (float(*)[68])(smemf + 32 * 68);
  int t = threadIdx.x;
  int tm = t >> 4, tn = t & 15;
  float acc[4][4] = {};
  for (int k0 = 0; k0 < D_IN; k0 += 32) {
#pragma unroll
    for (int i = 0; i < 2; i++) {
      int idx = t + 256 * i;
      int row = idx >> 3, c4 = idx & 7;
      float4 v = *reinterpret_cast<const float4*>(
          x + (size_t)(bm * 64 + row) * D_IN + k0 + c4 * 4);
      As[c4 * 4 + 0][row] = v.x;
      As[c4 * 4 + 1][row] = v.y;
      As[c4 * 4 + 2][row] = v.z;
      As[c4 * 4 + 3][row] = v.w;
      int brow = idx >> 4, bc4 = idx & 15;
      float4 wv = *reinterpret_cast<const float4*>(
          Wg1 + (size_t)(k0 + brow) * G_DIM + bn * 64 + bc4 * 4);
      *reinterpret_cast<float4*>(&Bs[brow][bc4 * 4]) = wv;
    }
    __syncthreads();
#pragma unroll
    for (int k = 0; k < 32; k++) {
      float4 av = *reinterpret_cast<const float4*>(&As[k][tm * 4]);
      float4 bv = *reinterpret_cast<const float4*>(&Bs[k][tn * 4]);
      float a4[4] = {av.x, av.y, av.z, av.w};
      float b4[4] = {bv.x, bv.y, bv.z, bv.w};
#pragma unroll
      for (int r = 0; r < 4; r++)
#pragma unroll
        for (int c = 0; c < 4; c++) acc[r][c] = fmaf(a4[r], b4[c], acc[r][c]);
    }
    __syncthreads();
  }
  int gr = bm * 64 + tm * 4, gc = bn * 64 + tn * 4;
#pragma unroll
  for (int r = 0; r < 4; r++) {
    float4 o;
    o.x = fmaxf(acc[r][0] + bg1[gc + 0], 0.f);
    o.y = fmaxf(acc[r][1] + bg1[gc + 1], 0.f);
    o.z = fmaxf(acc[r][2] + bg1[gc + 2], 0.f);
    o.w = fmaxf(acc[r][3] + bg1[gc + 3], 0.f);
    *reinterpret_cast<float4*>(g + (size_t)(gr + r) * G_DIM + gc) = o;
  }
}

__global__ __launch_bounds__(256) void prep_kernel(
    const float* __restrict__ x, __bf16* __restrict__ xb,
    const float* __restrict__ W1, __bf16* __restrict__ W1t,
    const float* __restrict__ Wg1, const float* __restrict__ bg1,
    float* __restrict__ g) {
  __shared__ float smemf[4352];  // 17408 B (gate1 needs 2x32x68)
  int b = blockIdx.x;
  if (b < JOB_G1_END) {
    gate1_body(x, Wg1, bg1, g, b & 3, b >> 2, smemf);
  } else if (b < JOB_CAST_END) {
    int id = b - JOB_G1_END;
    int i = id * 2048 + threadIdx.x * 8;
    float4 v0 = *reinterpret_cast<const float4*>(x + i);
    float4 v1 = *reinterpret_cast<const float4*>(x + i + 4);
    bf16x8 o;
    o[0] = (__bf16)v0.x; o[1] = (__bf16)v0.y; o[2] = (__bf16)v0.z; o[3] = (__bf16)v0.w;
    o[4] = (__bf16)v1.x; o[5] = (__bf16)v1.y; o[6] = (__bf16)v1.z; o[7] = (__bf16)v1.w;
    *reinterpret_cast<bf16x8*>(xb + i) = o;
  } else {
    int id = b - JOB_CAST_END;  // 32 n x 16 k x 8 e
    transpose_body(W1, W1t, D_IN, H_DIM, id >> 9, (id >> 5) & 15, id & 31, smemf);
  }
}

// ---------------- gate layer 2 + softmax/top2/renorm ----------------
__global__ __launch_bounds__(256) void gate2_kernel(const float* __restrict__ g,
                                                    const float* __restrict__ Wg2,
                                                    const float* __restrict__ bg2,
                                                    int* __restrict__ top_idx,
                                                    float* __restrict__ top_w,
                                                    int* __restrict__ counts) {
  __shared__ float lg[32][9];
  int t = threadIdx.x;
  int tl = t >> 3, e = t & 7;
  int n = blockIdx.x * 32 + tl;
  const float* gr = g + (size_t)n * G_DIM;
  float acc = bg2[e];
  for (int i = 0; i < G_DIM; i += 4) {
    float4 v = *reinterpret_cast<const float4*>(gr + i);
    acc += v.x * Wg2[(i + 0) * E_NUM + e];
    acc += v.y * Wg2[(i + 1) * E_NUM + e];
    acc += v.z * Wg2[(i + 2) * E_NUM + e];
    acc += v.w * Wg2[(i + 3) * E_NUM + e];
  }
  lg[tl][e] = acc;
  __syncthreads();
  if (e == 0) {
    float l[8];
#pragma unroll
    for (int i = 0; i < 8; i++) l[i] = lg[tl][i];
    int i0 = 0;
    for (int i = 1; i < 8; i++)
      if (l[i] > l[i0]) i0 = i;           // first-occurrence max (matches top_k tiebreak)
    int i1 = (i0 == 0) ? 1 : 0;
    for (int i = 0; i < 8; i++)
      if (i != i0 && l[i] > l[i1]) i1 = i;
    float d = expf(l[i1] - l[i0]);
    float w0 = 1.f / (1.f + d);
    float w1 = d * w0;
    top_idx[n * 2 + 0] = i0;
    top_idx[n * 2 + 1] = i1;
    top_w[n * 2 + 0] = w0;
    top_w[n * 2 + 1] = w1;
    atomicAdd(&counts[i0], 1);
    atomicAdd(&counts[i1], 1);
  }
}

// ---------------- prefix/tiles/aux-loss + pad-slot init (single block) ----------------
__global__ void g3_kernel(const int* __restrict__ counts, int* __restrict__ cursors,
                          int* __restrict__ off_pad, int* __restrict__ ntiles,
                          int* __restrict__ tile_meta, float* __restrict__ out_tail,
                          int* __restrict__ slot_token, float* __restrict__ slot_w) {
  if (threadIdx.x == 0) {
    int off = 0, nt = 0;
    float mse = 0.f;
    for (int e = 0; e < E_NUM; e++) {
      off_pad[e] = off;
      int c = counts[e];
      int tiles = (c + 127) >> 7;
      for (int i = 0; i < tiles; i++) {
        tile_meta[nt * 2 + 0] = e;
        tile_meta[nt * 2 + 1] = off + i * 128;
        nt++;
      }
      off += tiles << 7;
      cursors[e] = 0;
      float u = (float)c / (float)N_TOK;
      out_tail[1 + e] = u;
      float dd = u - 0.125f;
      mse += dd * dd;
    }
    *ntiles = nt;
    out_tail[0] = (mse / 8.0f) * 0.01f; // balance_loss
  }
  // pad slots gather token 0 with weight 0 (their fused-combine adds are 0 * finite)
  for (int s = threadIdx.x; s < MAXROWS; s += 256) {
    slot_token[s] = 0;
    slot_w[s] = 0.f;
  }
}

// ---------------- scatter tokens into per-expert segments ----------------
__global__ __launch_bounds__(256) void scatter_kernel(const int* __restrict__ top_idx,
                                                      const float* __restrict__ top_w,
                                                      const int* __restrict__ off_pad,
                                                      int* __restrict__ cursors,
                                                      int* __restrict__ slot_token,
                                                      float* __restrict__ slot_w) {
  int n = blockIdx.x * 256 + threadIdx.x;
#pragma unroll
  for (int k = 0; k < 2; k++) {
    int e = top_idx[n * 2 + k];
    int pos = atomicAdd(&cursors[e], 1);
    int s = off_pad[e] + pos;
    slot_token[s] = n;
    slot_w[s] = top_w[n * 2 + k];
  }
}

// ---------------- expert GEMM: 128x128 tile, BK=64, bf16 MFMA 16x16x32 ----------------
// R2-exact structure: single buffer, stage -> barrier -> compute -> barrier
// (measured best of 7 structural variants: 189 us, MfmaUtil 32.6, conflicts 0).
// LDS rows of 64 bf16 (128 B); chunk (row, kch) at slot kch ^ (row&7) via
// inverse-swizzled GLOBAL source addr (gload_lds dest linear).  Fragment
// reads: 8 accesses/bank = b128 floor, conflict-free.
// Blocks with blockIdx.y >= MAXTILES (GEMM-1 launch only) run W2/W3 transposes,
// overlapping them with GEMM-1 compute.
// mode 0: h_out = relu(acc+bias) bf16
// mode 1 (FUSED COMBINE): atomicAdd(out[tok], slot_w * (acc+bias)) -- fp32 add
//   is commutative so the 2 contributions per token are order-independent;
//   out is zeroed by memset before this launch; pad slots have slot_w = 0.
__global__ __launch_bounds__(256) void moe_gemm_kernel(
    const __bf16* __restrict__ A, int Astride, int gatherA,
    const __bf16* __restrict__ Wt, const float* __restrict__ bias,
    int Kdim, int Ndim,
    const int* __restrict__ tile_meta, const int* __restrict__ ntiles_p,
    const int* __restrict__ slot_token, const float* __restrict__ slot_w,
    __bf16* __restrict__ h_out, float* __restrict__ out_f, int finalMode,
    const float* __restrict__ W2src, __bf16* __restrict__ W2dst,
    const float* __restrict__ W3src, __bf16* __restrict__ W3dst) {
  __shared__ __align__(16) char smem[32768];
  int tile = blockIdx.y;
  if (tile >= MAXTILES) {
    int id = (tile - MAXTILES) * gridDim.x + blockIdx.x;  // 0..12287
    if (id < 8192) {
      // W2: 8 e x 32 ktile x 32 ntile
      transpose_body(W2src, W2dst, H_DIM, H_DIM, id >> 10, (id >> 5) & 31,
                     id & 31, (float*)smem);
    } else {
      id -= 8192;  // W3: 8 e x 32 ktile x 16 ntile
      transpose_body(W3src, W3dst, H_DIM, O_DIM, id >> 9, (id >> 4) & 31,
                     id & 15, (float*)smem);
    }
    return;
  }
  if (tile >= *ntiles_p) return;
  __bf16* As = (__bf16*)smem;            // 128 x 64 bf16 = 16384 B
  __bf16* Bs = (__bf16*)(smem + 16384);  // 128 x 64 bf16 = 16384 B
  int ex = tile_meta[tile * 2 + 0];
  int slot0 = tile_meta[tile * 2 + 1];
  int n0 = blockIdx.x * 128;
  int t = threadIdx.x, l = t & 63, w = t >> 6;

  size_t aoff[4], boff[4];
#pragma unroll
  for (int i = 0; i < 4; i++) {
    int gidx = (w * 4 + i) * 64 + l;
    int row = gidx >> 3;
    int kch = (gidx & 7) ^ (row & 7);
    int sl = slot0 + row;
    long long rb = gatherA ? (long long)slot_token[sl] * Astride
                           : (long long)sl * Astride;
    aoff[i] = (size_t)rb + kch * 8;
    boff[i] = ((size_t)ex * Ndim + n0 + row) * (size_t)Kdim + kch * 8;
  }

  int wm = (w >> 1) * 64, wn = (w & 1) * 64;
  int lm = l & 15, lq = l >> 4;
  floatx4 acc[4][4] = {};

  for (int k0 = 0; k0 < Kdim; k0 += 64) {
#pragma unroll
    for (int i = 0; i < 4; i++) {
      __builtin_amdgcn_global_load_lds(GCAST(A + aoff[i] + k0),
                                       LCAST((char*)As + w * 4096 + i * 1024),
                                       16, 0, 0);
      __builtin_amdgcn_global_load_lds(GCAST(Wt + boff[i] + k0),
                                       LCAST((char*)Bs + w * 4096 + i * 1024),
                                       16, 0, 0);
    }
    __syncthreads();
#pragma unroll
    for (int half = 0; half < 2; half++) {
      bf16x8 af[4], bfr[4];
#pragma unroll
      for (int i = 0; i < 4; i++) {
        int r = wm + i * 16 + lm;
        int s = (half * 4 + lq) ^ (r & 7);
        af[i] = *reinterpret_cast<const bf16x8*>(As + r * 64 + s * 8);
      }
#pragma unroll
      for (int j = 0; j < 4; j++) {
        int r = wn + j * 16 + lm;
        int s = (half * 4 + lq) ^ (r & 7);
        bfr[j] = *reinterpret_cast<const bf16x8*>(Bs + r * 64 + s * 8);
      }
#pragma unroll
      for (int i = 0; i < 4; i++)
#pragma unroll
        for (int j = 0; j < 4; j++)
          acc[i][j] = __builtin_amdgcn_mfma_f32_16x16x32_bf16(af[i], bfr[j],
                                                              acc[i][j], 0, 0, 0);
    }
    __syncthreads();
  }

  // epilogue: C/D layout col=lane&15, row=(lane>>4)*4+reg  [m89-verified]
  float bcol[4];
#pragma unroll
  for (int j = 0; j < 4; j++) bcol[j] = bias[(size_t)ex * Ndim + n0 + wn + j * 16 + lm];

  if (finalMode) {
#pragma unroll
    for (int i = 0; i < 4; i++) {
#pragma unroll
      for (int r = 0; r < 4; r++) {
        int sl = slot0 + wm + i * 16 + lq * 4 + r;
        int tok = slot_token[sl];
        float wgt = slot_w[sl];
        float* orow = out_f + (size_t)tok * Ndim + n0 + wn + lm;
#pragma unroll
        for (int j = 0; j < 4; j++)
          atomicAdd(&orow[j * 16], wgt * (acc[i][j][r] + bcol[j]));
      }
    }
  } else {
#pragma unroll
    for (int i = 0; i < 4; i++) {
#pragma unroll
      for (int r = 0; r < 4; r++) {
        int sl = slot0 + wm + i * 16 + lq * 4 + r;
        __bf16* hrow = h_out + (size_t)sl * Ndim + n0 + wn + lm;
#pragma unroll
        for (int j = 0; j < 4; j++) {
          float v = fmaxf(acc[i][j][r] + bcol[j], 0.f);
          hrow[j * 16] = (__bf16)v;
        }
      }
    }
  }
}

// ---------------- launch ----------------
extern "C" void kernel_launch(void* const* d_in, const int* in_sizes, int n_in,
                              void* d_out, int out_size, void* d_ws, size_t ws_size,
                              hipStream_t stream) {
  const float* x   = (const float*)d_in[0];
  const float* Wg1 = (const float*)d_in[1];
  const float* bg1 = (const float*)d_in[2];
  const float* Wg2 = (const float*)d_in[3];
  const float* bg2 = (const float*)d_in[4];
  const float* W1  = (const float*)d_in[5];
  const float* b1  = (const float*)d_in[6];
  const float* W2  = (const float*)d_in[7];
  const float* b2  = (const float*)d_in[8];
  const float* W3  = (const float*)d_in[9];
  const float* b3  = (const float*)d_in[10];
  float* out = (float*)d_out;

  char* ws = (char*)d_ws;
  __bf16* x_bf       = (__bf16*)(ws + 0);          // 16,777,216
  __bf16* W1t        = (__bf16*)(ws + 16777216);   // 33,554,432
  __bf16* W2t        = (__bf16*)(ws + 50331648);   // 67,108,864
  __bf16* W3t        = (__bf16*)(ws + 117440512);  // 33,554,432
  __bf16* h1         = (__bf16*)(ws + 150994944);  // 71,303,168
  __bf16* h2         = (__bf16*)(ws + 222298112);  // 71,303,168
  float*  gbuf       = (float*) (ws + 293601280);  // 8,388,608
  int*    top_idx    = (int*)   (ws + 301989888);  // 65,536
  float*  top_w      = (float*) (ws + 302055424);  // 65,536
  int*    slot_token = (int*)   (ws + 302120960);  // 69,632
  float*  slot_w     = (float*) (ws + 302190592);  // 69,632
  int*    meta       = (int*)   (ws + 302260224);
  int* counts    = meta;       // 8
  int* cursors   = meta + 8;   // 8
  int* off_pad   = meta + 16;  // 8
  int* ntiles    = meta + 24;  // 1
  int* tile_meta = meta + 32;  // 272
  float* out_tail = out + (size_t)N_TOK * O_DIM;   // [balance_loss, usage x8]

  hipMemsetAsync(meta, 0, 64, stream);                              // counts+cursors
  hipMemsetAsync(out, 0, (size_t)N_TOK * O_DIM * sizeof(float), stream);  // fused-combine acc

  prep_kernel<<<JOB_W1_END, 256, 0, stream>>>(x, x_bf, W1, W1t, Wg1, bg1, gbuf);
  gate2_kernel<<<N_TOK / 32, 256, 0, stream>>>(gbuf, Wg2, bg2, top_idx, top_w, counts);
  g3_kernel<<<1, 256, 0, stream>>>(counts, cursors, off_pad, ntiles, tile_meta, out_tail,
                                   slot_token, slot_w);
  scatter_kernel<<<N_TOK / 256, 256, 0, stream>>>(top_idx, top_w, off_pad, cursors,
                                                  slot_token, slot_w);

  // GEMM-1 launch carries the W2/W3 transpose jobs: 12288 extra blocks
  // (8192 W2 + 4096 W3) dispatched AFTER the GEMM tiles -> they fill spare
  // CUs/HBM while GEMM-1 computes; stream order still guarantees W2t/W3t
  // are complete before GEMM-2/3.
  moe_gemm_kernel<<<dim3(H_DIM / 128, MAXTILES + 768), 256, 0, stream>>>(
      x_bf, D_IN, 1, W1t, b1, D_IN, H_DIM, tile_meta, ntiles, slot_token, slot_w,
      h1, nullptr, 0, W2, W2t, W3, W3t);
  moe_gemm_kernel<<<dim3(H_DIM / 128, MAXTILES), 256, 0, stream>>>(
      h1, H_DIM, 0, W2t, b2, H_DIM, H_DIM, tile_meta, ntiles, slot_token, slot_w,
      h2, nullptr, 0, nullptr, nullptr, nullptr, nullptr);
  moe_gemm_kernel<<<dim3(O_DIM / 128, MAXTILES), 256, 0, stream>>>(
      h2, H_DIM, 0, W3t, b3, H_DIM, O_DIM, tile_meta, ntiles, slot_token, slot_w,
      nullptr, out, 1, nullptr, nullptr, nullptr, nullptr);
}

// Round 10
// 932.372 us; speedup vs baseline: 1.2401x; 1.2401x over previous
//
#include <hip/hip_runtime.h>
#include <hip/hip_bf16.h>
#include <cstdint>
#include <cstddef>

// MoE: N=8192 tokens, D=1024, H=2048, O=1024, E=8 experts, G=256 gate hidden, K=2
#define N_TOK 8192
#define D_IN  1024
#define H_DIM 2048
#define O_DIM 1024
#define E_NUM 8
#define G_DIM 256
#define MAXTILES 136            // ceil(16384/128) + 8 experts padding worst case
#define MAXROWS  (MAXTILES*128) // 17408

typedef __attribute__((ext_vector_type(8))) __bf16 bf16x8;
typedef __attribute__((ext_vector_type(4))) float floatx4;

#define GCAST(p) ((__attribute__((address_space(1))) void*)(void*)(p))
#define LCAST(p) ((__attribute__((address_space(3))) void*)(p))

// ---- fused prep kernel: gate1 (512) | cast_x (4096) | trW1 (4096)
#define JOB_G1_END   512
#define JOB_CAST_END 4608
#define JOB_W1_END   8704

// 64x64 fp32 transpose tile, rotation-swizzled: element (r, c) stored at
// tl[r][(c + 8*(r>>3)) & 63].  Reads (8 rows kg*8+j, col c) hit 2 lanes/bank;
// output writes are 128 B contiguous per row (8 lanes x 16 B).
__device__ inline void transpose_body(const float* __restrict__ src,
                                      __bf16* __restrict__ dst,
                                      int K, int N, int e, int ktile, int ntile,
                                      float* smemf) {
  float (*tl)[64] = (float(*)[64])smemf;  // 16384 B
  const float* s = src + (size_t)e * K * N;
  __bf16* d = dst + (size_t)e * K * N;
  int k0 = ktile * 64, n0 = ntile * 64;
  int t = threadIdx.x;
  int kr = t >> 4, nc = t & 15;
#pragma unroll
  for (int p = 0; p < 4; p++) {
    int r = kr + p * 16;
    float4 v = *reinterpret_cast<const float4*>(
        s + (size_t)(k0 + r) * N + n0 + nc * 4);
    *reinterpret_cast<float4*>(&tl[r][(nc * 4 + 8 * (r >> 3)) & 63]) = v;
  }
  __syncthreads();
  int n = t >> 3, kg = t & 7;
#pragma unroll
  for (int p = 0; p < 2; p++) {
    int c = n + p * 32;
    bf16x8 o;
#pragma unroll
    for (int j = 0; j < 8; j++)
      o[j] = (__bf16)tl[kg * 8 + j][(c + 8 * kg) & 63];
    *reinterpret_cast<bf16x8*>(d + (size_t)(n0 + c) * K + k0 + kg * 8) = o;
  }
}

__device__ inline void gate1_body(const float* __restrict__ x,
                                  const float* __restrict__ Wg1,
                                  const float* __restrict__ bg1,
                                  float* __restrict__ g,
                                  int bn, int bm, float* smemf) {
  float (*As)[68] = (float(*)[68])smemf;            // 32 x 68
  float (*Bs)[68] = (float(*)[68])(smemf + 32 * 68);
  int t = threadIdx.x;
  int tm = t >> 4, tn = t & 15;
  float acc[4][4] = {};
  for (int k0 = 0; k0 < D_IN; k0 += 32) {
#pragma unroll
    for (int i = 0; i < 2; i++) {
      int idx = t + 256 * i;
      int row = idx >> 3, c4 = idx & 7;
      float4 v = *reinterpret_cast<const float4*>(
          x + (size_t)(bm * 64 + row) * D_IN + k0 + c4 * 4);
      As[c4 * 4 + 0][row] = v.x;
      As[c4 * 4 + 1][row] = v.y;
      As[c4 * 4 + 2][row] = v.z;
      As[c4 * 4 + 3][row] = v.w;
      int brow = idx >> 4, bc4 = idx & 15;
      float4 wv = *reinterpret_cast<const float4*>(
          Wg1 + (size_t)(k0 + brow) * G_DIM + bn * 64 + bc4 * 4);
      *reinterpret_cast<float4*>(&Bs[brow][bc4 * 4]) = wv;
    }
    __syncthreads();
#pragma unroll
    for (int k = 0; k < 32; k++) {
      float4 av = *reinterpret_cast<const float4*>(&As[k][tm * 4]);
      float4 bv = *reinterpret_cast<const float4*>(&Bs[k][tn * 4]);
      float a4[4] = {av.x, av.y, av.z, av.w};
      float b4[4] = {bv.x, bv.y, bv.z, bv.w};
#pragma unroll
      for (int r = 0; r < 4; r++)
#pragma unroll
        for (int c = 0; c < 4; c++) acc[r][c] = fmaf(a4[r], b4[c], acc[r][c]);
    }
    __syncthreads();
  }
  int gr = bm * 64 + tm * 4, gc = bn * 64 + tn * 4;
#pragma unroll
  for (int r = 0; r < 4; r++) {
    float4 o;
    o.x = fmaxf(acc[r][0] + bg1[gc + 0], 0.f);
    o.y = fmaxf(acc[r][1] + bg1[gc + 1], 0.f);
    o.z = fmaxf(acc[r][2] + bg1[gc + 2], 0.f);
    o.w = fmaxf(acc[r][3] + bg1[gc + 3], 0.f);
    *reinterpret_cast<float4*>(g + (size_t)(gr + r) * G_DIM + gc) = o;
  }
}

__global__ __launch_bounds__(256) void prep_kernel(
    const float* __restrict__ x, __bf16* __restrict__ xb,
    const float* __restrict__ W1, __bf16* __restrict__ W1t,
    const float* __restrict__ Wg1, const float* __restrict__ bg1,
    float* __restrict__ g) {
  __shared__ float smemf[4352];  // 17408 B (gate1 needs 2x32x68)
  int b = blockIdx.x;
  if (b < JOB_G1_END) {
    gate1_body(x, Wg1, bg1, g, b & 3, b >> 2, smemf);
  } else if (b < JOB_CAST_END) {
    int id = b - JOB_G1_END;
    int i = id * 2048 + threadIdx.x * 8;
    float4 v0 = *reinterpret_cast<const float4*>(x + i);
    float4 v1 = *reinterpret_cast<const float4*>(x + i + 4);
    bf16x8 o;
    o[0] = (__bf16)v0.x; o[1] = (__bf16)v0.y; o[2] = (__bf16)v0.z; o[3] = (__bf16)v0.w;
    o[4] = (__bf16)v1.x; o[5] = (__bf16)v1.y; o[6] = (__bf16)v1.z; o[7] = (__bf16)v1.w;
    *reinterpret_cast<bf16x8*>(xb + i) = o;
  } else {
    int id = b - JOB_CAST_END;  // 32 n x 16 k x 8 e
    transpose_body(W1, W1t, D_IN, H_DIM, id >> 9, (id >> 5) & 15, id & 31, smemf);
  }
}

// ---------------- gate layer 2 + softmax/top2/renorm ----------------
__global__ __launch_bounds__(256) void gate2_kernel(const float* __restrict__ g,
                                                    const float* __restrict__ Wg2,
                                                    const float* __restrict__ bg2,
                                                    int* __restrict__ top_idx,
                                                    float* __restrict__ top_w,
                                                    int* __restrict__ counts) {
  __shared__ float lg[32][9];
  int t = threadIdx.x;
  int tl = t >> 3, e = t & 7;
  int n = blockIdx.x * 32 + tl;
  const float* gr = g + (size_t)n * G_DIM;
  float acc = bg2[e];
  for (int i = 0; i < G_DIM; i += 4) {
    float4 v = *reinterpret_cast<const float4*>(gr + i);
    acc += v.x * Wg2[(i + 0) * E_NUM + e];
    acc += v.y * Wg2[(i + 1) * E_NUM + e];
    acc += v.z * Wg2[(i + 2) * E_NUM + e];
    acc += v.w * Wg2[(i + 3) * E_NUM + e];
  }
  lg[tl][e] = acc;
  __syncthreads();
  if (e == 0) {
    float l[8];
#pragma unroll
    for (int i = 0; i < 8; i++) l[i] = lg[tl][i];
    int i0 = 0;
    for (int i = 1; i < 8; i++)
      if (l[i] > l[i0]) i0 = i;           // first-occurrence max (matches top_k tiebreak)
    int i1 = (i0 == 0) ? 1 : 0;
    for (int i = 0; i < 8; i++)
      if (i != i0 && l[i] > l[i1]) i1 = i;
    float d = expf(l[i1] - l[i0]);
    float w0 = 1.f / (1.f + d);
    float w1 = d * w0;
    top_idx[n * 2 + 0] = i0;
    top_idx[n * 2 + 1] = i1;
    top_w[n * 2 + 0] = w0;
    top_w[n * 2 + 1] = w1;
    atomicAdd(&counts[i0], 1);
    atomicAdd(&counts[i1], 1);
  }
}

// ---------------- prefix/tiles/aux-loss + pad-slot init (single block) ----------------
__global__ void g3_kernel(const int* __restrict__ counts, int* __restrict__ cursors,
                          int* __restrict__ off_pad, int* __restrict__ ntiles,
                          int* __restrict__ tile_meta, float* __restrict__ out_tail,
                          int* __restrict__ slot_token) {
  if (threadIdx.x == 0) {
    int off = 0, nt = 0;
    float mse = 0.f;
    for (int e = 0; e < E_NUM; e++) {
      off_pad[e] = off;
      int c = counts[e];
      int tiles = (c + 127) >> 7;
      for (int i = 0; i < tiles; i++) {
        tile_meta[nt * 2 + 0] = e;
        tile_meta[nt * 2 + 1] = off + i * 128;
        nt++;
      }
      off += tiles << 7;
      cursors[e] = 0;
      float u = (float)c / (float)N_TOK;
      out_tail[1 + e] = u;
      float dd = u - 0.125f;
      mse += dd * dd;
    }
    *ntiles = nt;
    out_tail[0] = (mse / 8.0f) * 0.01f; // balance_loss
  }
  // pad slots gather token 0 (harmless; their y rows are never combined)
  for (int s = threadIdx.x; s < MAXROWS; s += 256) slot_token[s] = 0;
}

// ---------------- scatter tokens into per-expert segments ----------------
__global__ __launch_bounds__(256) void scatter_kernel(const int* __restrict__ top_idx,
                                                      const int* __restrict__ off_pad,
                                                      int* __restrict__ cursors,
                                                      int* __restrict__ slot_token,
                                                      int* __restrict__ token_slots) {
  int n = blockIdx.x * 256 + threadIdx.x;
#pragma unroll
  for (int k = 0; k < 2; k++) {
    int e = top_idx[n * 2 + k];
    int pos = atomicAdd(&cursors[e], 1);
    int s = off_pad[e] + pos;
    slot_token[s] = n;
    token_slots[n * 2 + k] = s;
  }
}

// ---------------- expert GEMM: 128x128 tile, BK=64, bf16 MFMA 16x16x32 ----------------
// Single-buffer 2-barrier loop — measured best of 8 structural variants this
// session (189 us on the L2 GEMM; dbuf/counted-vmcnt/ring/wide-tile/atomic
// variants all regressed or were null).  LDS rows of 64 bf16 (128 B); chunk
// (row, kch) at slot kch ^ (row&7) via inverse-swizzled GLOBAL source addr
// (gload_lds dest linear).  Fragment reads: 8 accesses/bank = b128 floor,
// conflict-free (SQ_LDS_BANK_CONFLICT = 0 measured).
// Blocks with blockIdx.y >= MAXTILES (only launched for GEMM-1) run W2/W3
// transpose jobs instead, overlapping them with GEMM-1 compute.
// mode 0: h_out = relu(acc+bias) bf16;  mode 1: y_out[slot] = acc+bias fp32
__global__ __launch_bounds__(256) void moe_gemm_kernel(
    const __bf16* __restrict__ A, int Astride, int gatherA,
    const __bf16* __restrict__ Wt, const float* __restrict__ bias,
    int Kdim, int Ndim,
    const int* __restrict__ tile_meta, const int* __restrict__ ntiles_p,
    const int* __restrict__ slot_token,
    __bf16* __restrict__ h_out, float* __restrict__ y_out, int finalMode,
    const float* __restrict__ W2src, __bf16* __restrict__ W2dst,
    const float* __restrict__ W3src, __bf16* __restrict__ W3dst) {
  __shared__ __align__(16) char smem[32768];
  int tile = blockIdx.y;
  if (tile >= MAXTILES) {
    int id = (tile - MAXTILES) * gridDim.x + blockIdx.x;  // 0..12287
    if (id < 8192) {
      // W2: 8 e x 32 ktile x 32 ntile
      transpose_body(W2src, W2dst, H_DIM, H_DIM, id >> 10, (id >> 5) & 31,
                     id & 31, (float*)smem);
    } else {
      id -= 8192;  // W3: 8 e x 32 ktile x 16 ntile
      transpose_body(W3src, W3dst, H_DIM, O_DIM, id >> 9, (id >> 4) & 31,
                     id & 15, (float*)smem);
    }
    return;
  }
  if (tile >= *ntiles_p) return;
  __bf16* As = (__bf16*)smem;            // 128 x 64 bf16 = 16384 B
  __bf16* Bs = (__bf16*)(smem + 16384);  // 128 x 64 bf16 = 16384 B
  int ex = tile_meta[tile * 2 + 0];
  int slot0 = tile_meta[tile * 2 + 1];
  int n0 = blockIdx.x * 128;
  int t = threadIdx.x, l = t & 63, w = t >> 6;

  size_t aoff[4], boff[4];
#pragma unroll
  for (int i = 0; i < 4; i++) {
    int gidx = (w * 4 + i) * 64 + l;
    int row = gidx >> 3;
    int kch = (gidx & 7) ^ (row & 7);
    int sl = slot0 + row;
    long long rb = gatherA ? (long long)slot_token[sl] * Astride
                           : (long long)sl * Astride;
    aoff[i] = (size_t)rb + kch * 8;
    boff[i] = ((size_t)ex * Ndim + n0 + row) * (size_t)Kdim + kch * 8;
  }

  int wm = (w >> 1) * 64, wn = (w & 1) * 64;
  int lm = l & 15, lq = l >> 4;
  floatx4 acc[4][4] = {};

  for (int k0 = 0; k0 < Kdim; k0 += 64) {
#pragma unroll
    for (int i = 0; i < 4; i++) {
      __builtin_amdgcn_global_load_lds(GCAST(A + aoff[i] + k0),
                                       LCAST((char*)As + w * 4096 + i * 1024),
                                       16, 0, 0);
      __builtin_amdgcn_global_load_lds(GCAST(Wt + boff[i] + k0),
                                       LCAST((char*)Bs + w * 4096 + i * 1024),
                                       16, 0, 0);
    }
    __syncthreads();
#pragma unroll
    for (int half = 0; half < 2; half++) {
      bf16x8 af[4], bfr[4];
#pragma unroll
      for (int i = 0; i < 4; i++) {
        int r = wm + i * 16 + lm;
        int s = (half * 4 + lq) ^ (r & 7);
        af[i] = *reinterpret_cast<const bf16x8*>(As + r * 64 + s * 8);
      }
#pragma unroll
      for (int j = 0; j < 4; j++) {
        int r = wn + j * 16 + lm;
        int s = (half * 4 + lq) ^ (r & 7);
        bfr[j] = *reinterpret_cast<const bf16x8*>(Bs + r * 64 + s * 8);
      }
#pragma unroll
      for (int i = 0; i < 4; i++)
#pragma unroll
        for (int j = 0; j < 4; j++)
          acc[i][j] = __builtin_amdgcn_mfma_f32_16x16x32_bf16(af[i], bfr[j],
                                                              acc[i][j], 0, 0, 0);
    }
    __syncthreads();
  }

  // epilogue: C/D layout col=lane&15, row=(lane>>4)*4+reg  [m89-verified]
  float bcol[4];
#pragma unroll
  for (int j = 0; j < 4; j++) bcol[j] = bias[(size_t)ex * Ndim + n0 + wn + j * 16 + lm];

  if (finalMode) {
#pragma unroll
    for (int i = 0; i < 4; i++) {
#pragma unroll
      for (int r = 0; r < 4; r++) {
        int sl = slot0 + wm + i * 16 + lq * 4 + r;
        float* yrow = y_out + (size_t)sl * Ndim + n0 + wn + lm;
#pragma unroll
        for (int j = 0; j < 4; j++) yrow[j * 16] = acc[i][j][r] + bcol[j];
      }
    }
  } else {
#pragma unroll
    for (int i = 0; i < 4; i++) {
#pragma unroll
      for (int r = 0; r < 4; r++) {
        int sl = slot0 + wm + i * 16 + lq * 4 + r;
        __bf16* hrow = h_out + (size_t)sl * Ndim + n0 + wn + lm;
#pragma unroll
        for (int j = 0; j < 4; j++) {
          float v = fmaxf(acc[i][j][r] + bcol[j], 0.f);
          hrow[j * 16] = (__bf16)v;
        }
      }
    }
  }
}

// ---------------- combine: out[n] = w0*y[s0] + w1*y[s1] (exact fp32, no atomics) ----------------
__global__ __launch_bounds__(256) void combine_kernel(const float* __restrict__ y,
                                                      const int* __restrict__ token_slots,
                                                      const float* __restrict__ top_w,
                                                      float* __restrict__ out) {
  int n = blockIdx.x;
  int t = threadIdx.x;
  int s0 = token_slots[n * 2 + 0], s1 = token_slots[n * 2 + 1];
  float w0 = top_w[n * 2 + 0], w1 = top_w[n * 2 + 1];
  float4 a = reinterpret_cast<const float4*>(y + (size_t)s0 * O_DIM)[t];
  float4 b = reinterpret_cast<const float4*>(y + (size_t)s1 * O_DIM)[t];
  float4 o;
  o.x = w0 * a.x + w1 * b.x;
  o.y = w0 * a.y + w1 * b.y;
  o.z = w0 * a.z + w1 * b.z;
  o.w = w0 * a.w + w1 * b.w;
  reinterpret_cast<float4*>(out + (size_t)n * O_DIM)[t] = o;
}

// ---------------- launch ----------------
extern "C" void kernel_launch(void* const* d_in, const int* in_sizes, int n_in,
                              void* d_out, int out_size, void* d_ws, size_t ws_size,
                              hipStream_t stream) {
  const float* x   = (const float*)d_in[0];
  const float* Wg1 = (const float*)d_in[1];
  const float* bg1 = (const float*)d_in[2];
  const float* Wg2 = (const float*)d_in[3];
  const float* bg2 = (const float*)d_in[4];
  const float* W1  = (const float*)d_in[5];
  const float* b1  = (const float*)d_in[6];
  const float* W2  = (const float*)d_in[7];
  const float* b2  = (const float*)d_in[8];
  const float* W3  = (const float*)d_in[9];
  const float* b3  = (const float*)d_in[10];
  float* out = (float*)d_out;

  char* ws = (char*)d_ws;
  __bf16* x_bf       = (__bf16*)(ws + 0);          // 16,777,216
  __bf16* W1t        = (__bf16*)(ws + 16777216);   // 33,554,432
  __bf16* W2t        = (__bf16*)(ws + 50331648);   // 67,108,864
  __bf16* W3t        = (__bf16*)(ws + 117440512);  // 33,554,432
  __bf16* h1         = (__bf16*)(ws + 150994944);  // 71,303,168
  __bf16* h2         = (__bf16*)(ws + 222298112);  // 71,303,168
  float*  y          = (float*) (ws + 150994944);  // aliases h1 (free after L2 reads it)
  float*  gbuf       = (float*) (ws + 293601280);  // 8,388,608
  int*    top_idx    = (int*)   (ws + 301989888);  // 65,536
  float*  top_w      = (float*) (ws + 302055424);  // 65,536
  int*    slot_token = (int*)   (ws + 302120960);  // 69,632
  int*    token_slots= (int*)   (ws + 302190592);  // 65,536
  int*    meta       = (int*)   (ws + 302260224);
  int* counts    = meta;       // 8
  int* cursors   = meta + 8;   // 8
  int* off_pad   = meta + 16;  // 8
  int* ntiles    = meta + 24;  // 1
  int* tile_meta = meta + 32;  // 272
  float* out_tail = out + (size_t)N_TOK * O_DIM;   // [balance_loss, usage x8]

  hipMemsetAsync(meta, 0, 64, stream); // zero counts+cursors

  prep_kernel<<<JOB_W1_END, 256, 0, stream>>>(x, x_bf, W1, W1t, Wg1, bg1, gbuf);
  gate2_kernel<<<N_TOK / 32, 256, 0, stream>>>(gbuf, Wg2, bg2, top_idx, top_w, counts);
  g3_kernel<<<1, 256, 0, stream>>>(counts, cursors, off_pad, ntiles, tile_meta, out_tail,
                                   slot_token);
  scatter_kernel<<<N_TOK / 256, 256, 0, stream>>>(top_idx, off_pad, cursors,
                                                  slot_token, token_slots);

  // GEMM-1 launch carries the W2/W3 transpose jobs: 12288 extra blocks
  // (8192 W2 + 4096 W3) dispatched AFTER the GEMM tiles -> they fill spare
  // CUs/HBM while GEMM-1 computes; stream order still guarantees W2t/W3t
  // are complete before GEMM-2/3.
  moe_gemm_kernel<<<dim3(H_DIM / 128, MAXTILES + 768), 256, 0, stream>>>(
      x_bf, D_IN, 1, W1t, b1, D_IN, H_DIM, tile_meta, ntiles, slot_token,
      h1, nullptr, 0, W2, W2t, W3, W3t);
  moe_gemm_kernel<<<dim3(H_DIM / 128, MAXTILES), 256, 0, stream>>>(
      h1, H_DIM, 0, W2t, b2, H_DIM, H_DIM, tile_meta, ntiles, slot_token,
      h2, nullptr, 0, nullptr, nullptr, nullptr, nullptr);
  moe_gemm_kernel<<<dim3(O_DIM / 128, MAXTILES), 256, 0, stream>>>(
      h2, H_DIM, 0, W3t, b3, H_DIM, O_DIM, tile_meta, ntiles, slot_token,
      nullptr, y, 1, nullptr, nullptr, nullptr, nullptr);
  combine_kernel<<<N_TOK, 256, 0, stream>>>(y, token_slots, top_w, out);
}